// Round 1
// baseline (4108.190 us; speedup 1.0000x reference)
//
#include <hip/hip_runtime.h>
#include <math.h>

// Problem constants (reference: B=4, T=2048, C=2048, fp32)
constexpr int B_ = 4;
constexpr int T_ = 2048;
constexpr int C_ = 2048;
constexpr int M_ = B_ * T_;          // 8192 rows
constexpr float EPS_ = 1e-5f;

// ---------------- LayerNorm: one block per (b,t) row ----------------
__global__ __launch_bounds__(256) void ln_kernel(const float* __restrict__ x,
                                                 const float* __restrict__ w,
                                                 const float* __restrict__ bias,
                                                 float* __restrict__ xt) {
    const int row = blockIdx.x;                 // [0, M_)
    const float* xr = x + (size_t)row * C_;
    const int tid = threadIdx.x;

    // 2048 floats = 512 float4; 256 threads -> 2 float4 each
    float4 v0 = ((const float4*)xr)[tid];
    float4 v1 = ((const float4*)xr)[tid + 256];

    float s = v0.x + v0.y + v0.z + v0.w + v1.x + v1.y + v1.z + v1.w;
    float q = v0.x*v0.x + v0.y*v0.y + v0.z*v0.z + v0.w*v0.w
            + v1.x*v1.x + v1.y*v1.y + v1.z*v1.z + v1.w*v1.w;

    // wave (64-lane) reduce
    #pragma unroll
    for (int off = 32; off > 0; off >>= 1) {
        s += __shfl_down(s, off, 64);
        q += __shfl_down(q, off, 64);
    }
    __shared__ float red[10];
    const int wid = tid >> 6, lane = tid & 63;
    if (lane == 0) { red[wid * 2] = s; red[wid * 2 + 1] = q; }
    __syncthreads();
    if (tid == 0) {
        float ts = 0.f, tq = 0.f;
        #pragma unroll
        for (int i = 0; i < 4; ++i) { ts += red[i * 2]; tq += red[i * 2 + 1]; }
        const float mu = ts / (float)C_;
        const float var = tq / (float)C_ - mu * mu;
        red[8] = mu;
        red[9] = rsqrtf(var + EPS_);
    }
    __syncthreads();
    const float mu = red[8], rstd = red[9];

    float4 w0 = ((const float4*)w)[tid];
    float4 w1 = ((const float4*)w)[tid + 256];
    float4 b0 = ((const float4*)bias)[tid];
    float4 b1 = ((const float4*)bias)[tid + 256];

    float4 o0, o1;
    o0.x = (v0.x - mu) * rstd * w0.x + b0.x;
    o0.y = (v0.y - mu) * rstd * w0.y + b0.y;
    o0.z = (v0.z - mu) * rstd * w0.z + b0.z;
    o0.w = (v0.w - mu) * rstd * w0.w + b0.w;
    o1.x = (v1.x - mu) * rstd * w1.x + b1.x;
    o1.y = (v1.y - mu) * rstd * w1.y + b1.y;
    o1.z = (v1.z - mu) * rstd * w1.z + b1.z;
    o1.w = (v1.w - mu) * rstd * w1.w + b1.w;

    float* outr = xt + (size_t)row * C_;
    ((float4*)outr)[tid] = o0;
    ((float4*)outr)[tid + 256] = o1;
}

// ---------------- NT-GEMM: Y[m,n] = sum_k A[m,k] * W[n,k] ----------------
// MIXA: A operand computed on the fly as prev + mix*(cur - prev) from xt rows
// SIG : sigmoid epilogue
constexpr int BM = 64, BN = 64, BK = 16;
constexpr int LDT = 68;   // padded leading dim (2-way bank alias = free)

template <bool MIXA, bool SIG>
__global__ __launch_bounds__(256) void gemm_nt(const float* __restrict__ A,
                                               const float* __restrict__ W,
                                               const float* __restrict__ mix,
                                               float* __restrict__ Y) {
    __shared__ float As[BK][LDT];
    __shared__ float Bs[BK][LDT];

    const int n0 = blockIdx.x * BN;
    const int m0 = blockIdx.y * BM;
    const int tid = threadIdx.x;
    const int tx = tid & 15;        // output col group
    const int ty = tid >> 4;        // output row group
    const int srow = tid >> 2;      // staging row 0..63
    const int skv = tid & 3;        // staging float4 index along K

    float acc[4][4] = {};

    for (int k0 = 0; k0 < C_; k0 += BK) {
        // ---- stage A tile (transposed: As[k][m]) ----
        {
            const int m = m0 + srow;
            const size_t abase = (size_t)m * C_ + k0 + skv * 4;
            float4 a;
            if (MIXA) {
                const float4 cur = *(const float4*)&A[abase];
                const float4 mx = *(const float4*)&mix[k0 + skv * 4];
                float4 prev = make_float4(0.f, 0.f, 0.f, 0.f);
                if ((m % T_) != 0)
                    prev = *(const float4*)&A[abase - (size_t)C_];
                a.x = prev.x + (cur.x - prev.x) * mx.x;
                a.y = prev.y + (cur.y - prev.y) * mx.y;
                a.z = prev.z + (cur.z - prev.z) * mx.z;
                a.w = prev.w + (cur.w - prev.w) * mx.w;
            } else {
                a = *(const float4*)&A[abase];
            }
            As[skv * 4 + 0][srow] = a.x;
            As[skv * 4 + 1][srow] = a.y;
            As[skv * 4 + 2][srow] = a.z;
            As[skv * 4 + 3][srow] = a.w;

            const float4 wv = *(const float4*)&W[(size_t)(n0 + srow) * C_ + k0 + skv * 4];
            Bs[skv * 4 + 0][srow] = wv.x;
            Bs[skv * 4 + 1][srow] = wv.y;
            Bs[skv * 4 + 2][srow] = wv.z;
            Bs[skv * 4 + 3][srow] = wv.w;
        }
        __syncthreads();

        #pragma unroll
        for (int kk = 0; kk < BK; ++kk) {
            const float4 a = *(const float4*)&As[kk][ty * 4];
            const float4 b = *(const float4*)&Bs[kk][tx * 4];
            const float av[4] = {a.x, a.y, a.z, a.w};
            const float bv[4] = {b.x, b.y, b.z, b.w};
            #pragma unroll
            for (int i = 0; i < 4; ++i)
                #pragma unroll
                for (int j = 0; j < 4; ++j)
                    acc[i][j] = fmaf(av[i], bv[j], acc[i][j]);
        }
        __syncthreads();
    }

    #pragma unroll
    for (int i = 0; i < 4; ++i) {
        float4 o = make_float4(acc[i][0], acc[i][1], acc[i][2], acc[i][3]);
        if (SIG) {
            o.x = 1.f / (1.f + expf(-o.x));
            o.y = 1.f / (1.f + expf(-o.y));
            o.z = 1.f / (1.f + expf(-o.z));
            o.w = 1.f / (1.f + expf(-o.w));
        }
        *(float4*)&Y[(size_t)(m0 + ty * 4 + i) * C_ + n0 + tx * 4] = o;
    }
}

// ---------------- WKV recurrence (serial over T, in-place k -> r*rwkv) ----
__global__ __launch_bounds__(256) void wkv_kernel(float* __restrict__ k,   // in: k, out: r*rwkv
                                                  const float* __restrict__ v,
                                                  const float* __restrict__ r,
                                                  const float* __restrict__ time_decay,
                                                  const float* __restrict__ time_first) {
    const int c = blockIdx.x * 256 + threadIdx.x;  // channel
    const int b = blockIdx.y;                      // batch
    const float decay = 1.f / (1.f + expf(-time_decay[c]));
    const float first = expf(time_first[c]);

    size_t base = (size_t)b * T_ * C_ + c;
    float state = 0.f;
    #pragma unroll 4
    for (int t = 0; t < T_; ++t) {
        const float kt = k[base];
        const float vt = v[base];
        const float rt = r[base];
        state = state * decay + kt;
        const float rwkv = (state * first + kt) * vt;
        k[base] = rt * rwkv;
        base += C_;
    }
}

// ---------------- launch ----------------
extern "C" void kernel_launch(void* const* d_in, const int* in_sizes, int n_in,
                              void* d_out, int out_size, void* d_ws, size_t ws_size,
                              hipStream_t stream) {
    const float* x          = (const float*)d_in[0];
    const float* ln_w       = (const float*)d_in[1];
    const float* ln_b       = (const float*)d_in[2];
    const float* mix_k      = (const float*)d_in[3];
    const float* mix_v      = (const float*)d_in[4];
    const float* mix_r      = (const float*)d_in[5];
    const float* time_decay = (const float*)d_in[6];
    const float* time_first = (const float*)d_in[7];
    const float* Wk         = (const float*)d_in[8];
    const float* Wv         = (const float*)d_in[9];
    const float* Wr         = (const float*)d_in[10];
    const float* Wo         = (const float*)d_in[11];
    float* out = (float*)d_out;

    const size_t planeElems = (size_t)M_ * C_;     // 16.7M floats, 64 MB
    float* xt = (float*)d_ws;
    float* kb = xt + planeElems;
    float* vb = kb + planeElems;
    float* rb = vb + planeElems;

    // 1. LayerNorm
    ln_kernel<<<M_, 256, 0, stream>>>(x, ln_w, ln_b, xt);

    // 2. three projections (mix fused into A staging)
    dim3 ggrid(C_ / BN, M_ / BM);
    gemm_nt<true, false><<<ggrid, 256, 0, stream>>>(xt, Wk, mix_k, kb);
    gemm_nt<true, false><<<ggrid, 256, 0, stream>>>(xt, Wv, mix_v, vb);
    gemm_nt<true, true ><<<ggrid, 256, 0, stream>>>(xt, Wr, mix_r, rb);

    // 3. WKV recurrence + elementwise, writes r*rwkv in-place over kb
    wkv_kernel<<<dim3(C_ / 256, B_), 256, 0, stream>>>(kb, vb, rb, time_decay, time_first);

    // 4. output projection
    gemm_nt<false, false><<<ggrid, 256, 0, stream>>>(kb, Wo, nullptr, out);
}

// Round 2
// 1662.169 us; speedup vs baseline: 2.4716x; 2.4716x over previous
//
#include <hip/hip_runtime.h>
#include <math.h>

// RWKV6 block: LN -> {k,v,r} proj (time-mix fused) -> WKV recurrence -> out proj
// B=4, T=2048, C=2048, fp32. GEMMs on MFMA via split-bf16 (hi/lo) x3 emulation.
constexpr int B_ = 4;
constexpr int T_ = 2048;
constexpr int C_ = 2048;
constexpr int M_ = B_ * T_;          // 8192 rows
constexpr float EPS_ = 1e-5f;

typedef __attribute__((ext_vector_type(8))) short short8;   // bf16x8 MFMA operand
typedef __attribute__((ext_vector_type(4))) float f32x4;    // MFMA acc

// round-to-nearest-even fp32 -> bf16 (as ushort)
__device__ __forceinline__ unsigned short rne_bf16(float x) {
    unsigned u = __float_as_uint(x);
    unsigned r = u + 0x7FFFu + ((u >> 16) & 1u);
    return (unsigned short)(r >> 16);
}
__device__ __forceinline__ void split_bf16(float x, unsigned short& hi, unsigned short& lo) {
    hi = rne_bf16(x);
    float hf = __uint_as_float((unsigned)hi << 16);
    lo = rne_bf16(x - hf);
}

// ---------------- LayerNorm: one block per (b,t) row ----------------
__global__ __launch_bounds__(256) void ln_kernel(const float* __restrict__ x,
                                                 const float* __restrict__ w,
                                                 const float* __restrict__ bias,
                                                 float* __restrict__ xt) {
    const int row = blockIdx.x;
    const float* xr = x + (size_t)row * C_;
    const int tid = threadIdx.x;

    float4 v0 = ((const float4*)xr)[tid];
    float4 v1 = ((const float4*)xr)[tid + 256];

    float s = v0.x + v0.y + v0.z + v0.w + v1.x + v1.y + v1.z + v1.w;
    float q = v0.x*v0.x + v0.y*v0.y + v0.z*v0.z + v0.w*v0.w
            + v1.x*v1.x + v1.y*v1.y + v1.z*v1.z + v1.w*v1.w;

    #pragma unroll
    for (int off = 32; off > 0; off >>= 1) {
        s += __shfl_down(s, off, 64);
        q += __shfl_down(q, off, 64);
    }
    __shared__ float red[10];
    const int wid = tid >> 6, lane = tid & 63;
    if (lane == 0) { red[wid * 2] = s; red[wid * 2 + 1] = q; }
    __syncthreads();
    if (tid == 0) {
        float ts = 0.f, tq = 0.f;
        #pragma unroll
        for (int i = 0; i < 4; ++i) { ts += red[i * 2]; tq += red[i * 2 + 1]; }
        const float mu = ts / (float)C_;
        const float var = tq / (float)C_ - mu * mu;
        red[8] = mu;
        red[9] = rsqrtf(var + EPS_);
    }
    __syncthreads();
    const float mu = red[8], rstd = red[9];

    float4 w0 = ((const float4*)w)[tid];
    float4 w1 = ((const float4*)w)[tid + 256];
    float4 b0 = ((const float4*)bias)[tid];
    float4 b1 = ((const float4*)bias)[tid + 256];

    float4 o0, o1;
    o0.x = (v0.x - mu) * rstd * w0.x + b0.x;
    o0.y = (v0.y - mu) * rstd * w0.y + b0.y;
    o0.z = (v0.z - mu) * rstd * w0.z + b0.z;
    o0.w = (v0.w - mu) * rstd * w0.w + b0.w;
    o1.x = (v1.x - mu) * rstd * w1.x + b1.x;
    o1.y = (v1.y - mu) * rstd * w1.y + b1.y;
    o1.z = (v1.z - mu) * rstd * w1.z + b1.z;
    o1.w = (v1.w - mu) * rstd * w1.w + b1.w;

    float* outr = xt + (size_t)row * C_;
    ((float4*)outr)[tid] = o0;
    ((float4*)outr)[tid + 256] = o1;
}

// ---------------- W fp32 -> (hi, lo) bf16 planes ----------------
__global__ __launch_bounds__(256) void wconv_kernel(const float* __restrict__ W,
                                                    unsigned short* __restrict__ hi,
                                                    unsigned short* __restrict__ lo) {
    const int i = blockIdx.x * 256 + threadIdx.x;   // over C_*C_/4 float4s
    float4 w = ((const float4*)W)[i];
    ushort4 h, l;
    split_bf16(w.x, h.x, l.x);
    split_bf16(w.y, h.y, l.y);
    split_bf16(w.z, h.z, l.z);
    split_bf16(w.w, h.w, l.w);
    ((ushort4*)hi)[i] = h;
    ((ushort4*)lo)[i] = l;
}

// ---------------- MFMA GEMM: Y[m,n] = sum_k A[m,k] * W[n,k] ----------------
// A fp32 (optionally time-mixed on the fly), W pre-split into hi/lo bf16.
// acc += Ahi*Whi + Ahi*Wlo + Alo*Whi  (split-bf16; ~fp32 accuracy)
// 128x128 tile, BK=32, 256 threads = 4 waves, 64x64 per wave (4x4 of 16x16x32).
template <bool MIXA, bool SIG>
__global__ __launch_bounds__(256) void gemm_mfma(const float* __restrict__ A,
                                                 const float* __restrict__ mix,
                                                 const unsigned short* __restrict__ Whi,
                                                 const unsigned short* __restrict__ Wlo,
                                                 float* __restrict__ Y) {
    __shared__ unsigned short sAhi[128 * 32];
    __shared__ unsigned short sAlo[128 * 32];
    __shared__ unsigned short sBhi[128 * 32];
    __shared__ unsigned short sBlo[128 * 32];

    const int tid = threadIdx.x;
    const int lane = tid & 63;
    const int w = tid >> 6;            // wave 0..3
    const int wr = w >> 1, wc = w & 1; // wave quadrant (2x2 of 64x64)
    const int n0 = blockIdx.x * 128;
    const int m0 = blockIdx.y * 128;

    f32x4 acc[4][4] = {};

    // B staging (global_load_lds): chunk c covers rows 16c..16c+15, 1KB per call
    const int bc0 = w * 2;
    const int brow_l = lane >> 2;          // 0..15 within chunk
    const int bk_l = (lane & 3) * 8;       // bf16 elem offset in k

    // A staging: element j = tid + i*256 over 128x8 float4 tile
    const int arow = tid >> 3;             // 0..31 (per i: +32)
    const int akc = (tid & 7) * 4;         // fp32 col 0..28

    for (int k0 = 0; k0 < C_; k0 += 32) {
        // ---- stage W tiles via async global->LDS (16B/lane) ----
        #pragma unroll
        for (int i = 0; i < 2; ++i) {
            const int c = bc0 + i;
            const size_t gsrc = (size_t)(n0 + c * 16 + brow_l) * C_ + k0 + bk_l;
            __builtin_amdgcn_global_load_lds(
                (const __attribute__((address_space(1))) unsigned int*)&Whi[gsrc],
                (__attribute__((address_space(3))) unsigned int*)&sBhi[c * 512],
                16, 0, 0);
            __builtin_amdgcn_global_load_lds(
                (const __attribute__((address_space(1))) unsigned int*)&Wlo[gsrc],
                (__attribute__((address_space(3))) unsigned int*)&sBlo[c * 512],
                16, 0, 0);
        }

        // ---- stage A: load fp32, mix, split, ds_write ----
        #pragma unroll
        for (int i = 0; i < 4; ++i) {
            const int row = arow + i * 32;          // 0..127
            const int m = m0 + row;
            const size_t abase = (size_t)m * C_ + k0 + akc;
            const float4 cur = *(const float4*)&A[abase];
            float4 a = cur;
            if (MIXA) {
                const float4 mx = *(const float4*)&mix[k0 + akc];
                float4 prev = make_float4(0.f, 0.f, 0.f, 0.f);
                if ((m & (T_ - 1)) != 0)
                    prev = *(const float4*)&A[abase - (size_t)C_];
                a.x = prev.x + (cur.x - prev.x) * mx.x;
                a.y = prev.y + (cur.y - prev.y) * mx.y;
                a.z = prev.z + (cur.z - prev.z) * mx.z;
                a.w = prev.w + (cur.w - prev.w) * mx.w;
            }
            ushort4 h, l;
            split_bf16(a.x, h.x, l.x);
            split_bf16(a.y, h.y, l.y);
            split_bf16(a.z, h.z, l.z);
            split_bf16(a.w, h.w, l.w);
            *(ushort4*)&sAhi[row * 32 + akc] = h;
            *(ushort4*)&sAlo[row * 32 + akc] = l;
        }
        __syncthreads();   // drains vmcnt (gload_lds) + lgkmcnt (ds_write)

        // ---- fragments + MFMA ----
        short8 ahi[4], alo[4];
        const int fk = (lane >> 4) * 8;    // k offset of this lane's 8 elems
        const int fr = lane & 15;          // row/col within 16
        #pragma unroll
        for (int mi = 0; mi < 4; ++mi) {
            const int r = wr * 64 + mi * 16 + fr;
            ahi[mi] = *(const short8*)&sAhi[r * 32 + fk];
            alo[mi] = *(const short8*)&sAlo[r * 32 + fk];
        }
        #pragma unroll
        for (int ni = 0; ni < 4; ++ni) {
            const int r = wc * 64 + ni * 16 + fr;
            const short8 bhi = *(const short8*)&sBhi[r * 32 + fk];
            const short8 blo = *(const short8*)&sBlo[r * 32 + fk];
            #pragma unroll
            for (int mi = 0; mi < 4; ++mi) {
                acc[mi][ni] = __builtin_amdgcn_mfma_f32_16x16x32_bf16(ahi[mi], bhi, acc[mi][ni], 0, 0, 0);
                acc[mi][ni] = __builtin_amdgcn_mfma_f32_16x16x32_bf16(ahi[mi], blo, acc[mi][ni], 0, 0, 0);
                acc[mi][ni] = __builtin_amdgcn_mfma_f32_16x16x32_bf16(alo[mi], bhi, acc[mi][ni], 0, 0, 0);
            }
        }
        __syncthreads();
    }

    // ---- epilogue: C/D layout col=lane&15, row=(lane>>4)*4+reg ----
    const int fq = lane >> 4, fr = lane & 15;
    #pragma unroll
    for (int mi = 0; mi < 4; ++mi) {
        #pragma unroll
        for (int ni = 0; ni < 4; ++ni) {
            const int row = m0 + wr * 64 + mi * 16 + fq * 4;
            const int col = n0 + wc * 64 + ni * 16 + fr;
            #pragma unroll
            for (int r = 0; r < 4; ++r) {
                float v = acc[mi][ni][r];
                if (SIG) v = 1.f / (1.f + expf(-v));
                Y[(size_t)(row + r) * C_ + col] = v;
            }
        }
    }
}

// ---------------- WKV recurrence (serial over T, in-place k -> r*rwkv) ----
__global__ __launch_bounds__(256) void wkv_kernel(float* __restrict__ k,   // in: k, out: r*rwkv
                                                  const float* __restrict__ v,
                                                  const float* __restrict__ r,
                                                  const float* __restrict__ time_decay,
                                                  const float* __restrict__ time_first) {
    const int c = blockIdx.x * 256 + threadIdx.x;
    const int b = blockIdx.y;
    const float decay = 1.f / (1.f + expf(-time_decay[c]));
    const float first = expf(time_first[c]);

    size_t base = (size_t)b * T_ * C_ + c;
    float state = 0.f;
    #pragma unroll 4
    for (int t = 0; t < T_; ++t) {
        const float kt = k[base];
        const float vt = v[base];
        const float rt = r[base];
        state = state * decay + kt;
        const float rwkv = (state * first + kt) * vt;
        k[base] = rt * rwkv;
        base += C_;
    }
}

// ---------------- launch ----------------
extern "C" void kernel_launch(void* const* d_in, const int* in_sizes, int n_in,
                              void* d_out, int out_size, void* d_ws, size_t ws_size,
                              hipStream_t stream) {
    const float* x          = (const float*)d_in[0];
    const float* ln_w       = (const float*)d_in[1];
    const float* ln_b       = (const float*)d_in[2];
    const float* mix_k      = (const float*)d_in[3];
    const float* mix_v      = (const float*)d_in[4];
    const float* mix_r      = (const float*)d_in[5];
    const float* time_decay = (const float*)d_in[6];
    const float* time_first = (const float*)d_in[7];
    const float* Wk         = (const float*)d_in[8];
    const float* Wv         = (const float*)d_in[9];
    const float* Wr         = (const float*)d_in[10];
    const float* Wo         = (const float*)d_in[11];
    float* out = (float*)d_out;

    // ws layout: xt(64MB) kb(64MB) vb(64MB) Whi(8.4MB) Wlo(8.4MB)  ~209MB
    const size_t planeElems = (size_t)M_ * C_;
    float* xt = (float*)d_ws;
    float* kb = xt + planeElems;
    float* vb = kb + planeElems;
    unsigned short* whi = (unsigned short*)(vb + planeElems);
    unsigned short* wlo = whi + (size_t)C_ * C_;
    float* rb = out;   // r lives in d_out until consumed by WKV

    const dim3 ggrid(C_ / 128, M_ / 128);
    const int wcBlocks = (C_ * C_ / 4) / 256;

    // 1. LayerNorm
    ln_kernel<<<M_, 256, 0, stream>>>(x, ln_w, ln_b, xt);

    // 2. three projections (mix fused into A staging; W split per-GEMM)
    wconv_kernel<<<wcBlocks, 256, 0, stream>>>(Wk, whi, wlo);
    gemm_mfma<true, false><<<ggrid, 256, 0, stream>>>(xt, mix_k, whi, wlo, kb);
    wconv_kernel<<<wcBlocks, 256, 0, stream>>>(Wv, whi, wlo);
    gemm_mfma<true, false><<<ggrid, 256, 0, stream>>>(xt, mix_v, whi, wlo, vb);
    wconv_kernel<<<wcBlocks, 256, 0, stream>>>(Wr, whi, wlo);
    gemm_mfma<true, true ><<<ggrid, 256, 0, stream>>>(xt, mix_r, whi, wlo, rb);

    // 3. WKV recurrence + elementwise, writes r*rwkv in-place over kb
    wkv_kernel<<<dim3(C_ / 256, B_), 256, 0, stream>>>(kb, vb, rb, time_decay, time_first);

    // 4. output projection
    wconv_kernel<<<wcBlocks, 256, 0, stream>>>(Wo, whi, wlo);
    gemm_mfma<false, false><<<ggrid, 256, 0, stream>>>(kb, nullptr, whi, wlo, out);
}

// Round 3
// 1267.147 us; speedup vs baseline: 3.2421x; 1.3117x over previous
//
#include <hip/hip_runtime.h>
#include <math.h>

// RWKV6 block on MI355X. fp32 problem; GEMMs via split-bf16 (hi/lo) x3 MFMA emulation.
// B=4, T=2048, C=2048.
constexpr int B_ = 4;
constexpr int T_ = 2048;
constexpr int C_ = 2048;
constexpr int M_ = B_ * T_;          // 8192 rows
constexpr float EPS_ = 1e-5f;
constexpr int KSTEPS = C_ / 32;      // 64

typedef __attribute__((ext_vector_type(8))) short short8;   // bf16x8 MFMA operand
typedef __attribute__((ext_vector_type(4))) float f32x4;    // MFMA acc

__device__ __forceinline__ unsigned short rne_bf16(float x) {
    unsigned u = __float_as_uint(x);
    unsigned r = u + 0x7FFFu + ((u >> 16) & 1u);
    return (unsigned short)(r >> 16);
}
__device__ __forceinline__ void split_bf16(float x, unsigned short& hi, unsigned short& lo) {
    hi = rne_bf16(x);
    lo = rne_bf16(x - __uint_as_float((unsigned)hi << 16));
}

// ---------------- LayerNorm: one block per (b,t) row ----------------
__global__ __launch_bounds__(256) void ln_kernel(const float* __restrict__ x,
                                                 const float* __restrict__ w,
                                                 const float* __restrict__ bias,
                                                 float* __restrict__ xt) {
    const int row = blockIdx.x;
    const float* xr = x + (size_t)row * C_;
    const int tid = threadIdx.x;

    float4 v0 = ((const float4*)xr)[tid];
    float4 v1 = ((const float4*)xr)[tid + 256];

    float s = v0.x + v0.y + v0.z + v0.w + v1.x + v1.y + v1.z + v1.w;
    float q = v0.x*v0.x + v0.y*v0.y + v0.z*v0.z + v0.w*v0.w
            + v1.x*v1.x + v1.y*v1.y + v1.z*v1.z + v1.w*v1.w;

    #pragma unroll
    for (int off = 32; off > 0; off >>= 1) {
        s += __shfl_down(s, off, 64);
        q += __shfl_down(q, off, 64);
    }
    __shared__ float red[10];
    const int wid = tid >> 6, lane = tid & 63;
    if (lane == 0) { red[wid * 2] = s; red[wid * 2 + 1] = q; }
    __syncthreads();
    if (tid == 0) {
        float ts = 0.f, tq = 0.f;
        #pragma unroll
        for (int i = 0; i < 4; ++i) { ts += red[i * 2]; tq += red[i * 2 + 1]; }
        const float mu = ts / (float)C_;
        const float var = tq / (float)C_ - mu * mu;
        red[8] = mu;
        red[9] = rsqrtf(var + EPS_);
    }
    __syncthreads();
    const float mu = red[8], rstd = red[9];

    float4 w0 = ((const float4*)w)[tid];
    float4 w1 = ((const float4*)w)[tid + 256];
    float4 b0 = ((const float4*)bias)[tid];
    float4 b1 = ((const float4*)bias)[tid + 256];

    float4 o0, o1;
    o0.x = (v0.x - mu) * rstd * w0.x + b0.x;
    o0.y = (v0.y - mu) * rstd * w0.y + b0.y;
    o0.z = (v0.z - mu) * rstd * w0.z + b0.z;
    o0.w = (v0.w - mu) * rstd * w0.w + b0.w;
    o1.x = (v1.x - mu) * rstd * w1.x + b1.x;
    o1.y = (v1.y - mu) * rstd * w1.y + b1.y;
    o1.z = (v1.z - mu) * rstd * w1.z + b1.z;
    o1.w = (v1.w - mu) * rstd * w1.w + b1.w;

    float* outr = xt + (size_t)row * C_;
    ((float4*)outr)[tid] = o0;
    ((float4*)outr)[tid + 256] = o1;
}

// ---------------- time-mix + split to bf16 hi/lo planes ----------------
// a = prev + (cur - prev) * mix, over [M, C]; prev = row m-1 (0 at t=0)
__global__ __launch_bounds__(256) void mixsplit_kernel(const float* __restrict__ xt,
                                                       const float* __restrict__ mix,
                                                       unsigned short* __restrict__ hi,
                                                       unsigned short* __restrict__ lo) {
    const int i = blockIdx.x * 256 + threadIdx.x;   // over M_*C_/4 float4s
    const int m = i >> 9;                           // C_/4 = 512
    const int c4 = i & 511;
    const float4 cur = ((const float4*)xt)[i];
    const float4 mx = ((const float4*)mix)[c4];
    float4 prev = make_float4(0.f, 0.f, 0.f, 0.f);
    if ((m & (T_ - 1)) != 0) prev = ((const float4*)xt)[i - 512];
    float4 a;
    a.x = prev.x + (cur.x - prev.x) * mx.x;
    a.y = prev.y + (cur.y - prev.y) * mx.y;
    a.z = prev.z + (cur.z - prev.z) * mx.z;
    a.w = prev.w + (cur.w - prev.w) * mx.w;
    ushort4 h, l;
    split_bf16(a.x, h.x, l.x);
    split_bf16(a.y, h.y, l.y);
    split_bf16(a.z, h.z, l.z);
    split_bf16(a.w, h.w, l.w);
    ((ushort4*)hi)[i] = h;
    ((ushort4*)lo)[i] = l;
}

// ---------------- W fp32 -> (hi, lo) bf16 planes ----------------
__global__ __launch_bounds__(256) void wconv_kernel(const float* __restrict__ W,
                                                    unsigned short* __restrict__ hi,
                                                    unsigned short* __restrict__ lo) {
    const int i = blockIdx.x * 256 + threadIdx.x;   // over C_*C_/4 float4s
    float4 w = ((const float4*)W)[i];
    ushort4 h, l;
    split_bf16(w.x, h.x, l.x);
    split_bf16(w.y, h.y, l.y);
    split_bf16(w.z, h.z, l.z);
    split_bf16(w.w, h.w, l.w);
    ((ushort4*)hi)[i] = h;
    ((ushort4*)lo)[i] = l;
}

// ---------------- MFMA GEMM: Y[m,n] = sum_k A[m,k] * W[n,k] --------------
// A,W pre-split bf16 hi/lo planes. acc += Ah*Wh + Al*Wh + Ah*Wl.
// 256x256 tile, BK=32, 512 threads (8 waves, 2Mx4N), 128KB LDS double-buffer.
// LDS layout per region: 256 rows x 8 slots of 16B  (slots 0-3 = hi k-chunks,
// 4-7 = lo k-chunks), physical slot p = s ^ (row&7)  -> conflict-free ds_read.
// global_load_lds fills LDS LINEARLY by chunk index; the per-lane GLOBAL source
// address applies the inverse swizzle (rule 21: both-sides-or-neither).
template <bool SIG>
__global__ __launch_bounds__(512, 2) void gemm_mfma(const unsigned short* __restrict__ Ahi,
                                                    const unsigned short* __restrict__ Alo,
                                                    const unsigned short* __restrict__ Whi,
                                                    const unsigned short* __restrict__ Wlo,
                                                    float* __restrict__ Y) {
    __shared__ unsigned short lds[2][2][256 * 64];  // [dbuf][A/B][row*64 + phys*8] ushorts

    const int tid = threadIdx.x;
    const int lane = tid & 63;
    const int wid = tid >> 6;          // 0..7
    const int wr = wid >> 2;           // 0..1  (M half: 128 rows)
    const int wcn = wid & 3;           // 0..3  (N quarter: 64 cols)

    // XCD-chunked block swizzle: 256 blocks, 8 XCDs, 32/XCD -> 4Mx8N compact region
    const int bid = blockIdx.x;
    const int swz = (bid & 7) * 32 + (bid >> 3);
    const int m0 = (swz >> 3) * 256;
    const int n0 = (swz & 7) * 256;

    // ---- staging: 4 chunks (16B) per thread per region per K-step ----
    // chunk ci = j*512 + tid; r=ci>>3; p=ci&7; logical s=p^(r&7); plane=s>>2; ks=s&3
    const unsigned short* gA[4];
    const unsigned short* gB[4];
    #pragma unroll
    for (int j = 0; j < 4; ++j) {
        const int ci = j * 512 + tid;
        const int r = ci >> 3, p = ci & 7;
        const int s = p ^ (r & 7);
        const int pl = s >> 2, ks = s & 3;
        gA[j] = (pl ? Alo : Ahi) + (size_t)(m0 + r) * C_ + ks * 8;
        gB[j] = (pl ? Wlo : Whi) + (size_t)(n0 + r) * C_ + ks * 8;
    }
    const int stage_off = wid * 512;   // ushorts; + j*4096

    // ---- ds_read bases (ushort offsets within one region) ----
    const int fr = lane & 15;
    const int kg = lane >> 4;                 // 0..3 (k-chunk)
    const int pH = (kg + 0) ^ (fr & 7);       // hi plane slot
    const int pL = (kg + 4) ^ (fr & 7);       // lo plane slot
    const int baseA0 = (wr * 128 + fr) * 64 + pH * 8;
    const int baseA1 = (wr * 128 + fr) * 64 + pL * 8;
    const int baseB0 = (wcn * 64 + fr) * 64 + pH * 8;
    const int baseB1 = (wcn * 64 + fr) * 64 + pL * 8;

    f32x4 acc[8][4] = {};

    auto STAGE = [&](int buf, int t) {
        const int ko = t * 32;
        #pragma unroll
        for (int j = 0; j < 4; ++j)
            __builtin_amdgcn_global_load_lds(
                (const __attribute__((address_space(1))) unsigned int*)(gA[j] + ko),
                (__attribute__((address_space(3))) unsigned int*)&lds[buf][0][j * 4096 + stage_off],
                16, 0, 0);
        #pragma unroll
        for (int j = 0; j < 4; ++j)
            __builtin_amdgcn_global_load_lds(
                (const __attribute__((address_space(1))) unsigned int*)(gB[j] + ko),
                (__attribute__((address_space(3))) unsigned int*)&lds[buf][1][j * 4096 + stage_off],
                16, 0, 0);
    };

    auto COMPUTE = [&](int buf) {
        const unsigned short* LA = lds[buf][0];
        const unsigned short* LB = lds[buf][1];
        short8 bh[4], bl[4];
        #pragma unroll
        for (int ni = 0; ni < 4; ++ni) {
            bh[ni] = *(const short8*)&LB[baseB0 + ni * 1024];
            bl[ni] = *(const short8*)&LB[baseB1 + ni * 1024];
        }
        #pragma unroll
        for (int mi = 0; mi < 8; ++mi) {
            const short8 ah = *(const short8*)&LA[baseA0 + mi * 1024];
            const short8 al = *(const short8*)&LA[baseA1 + mi * 1024];
            #pragma unroll
            for (int ni = 0; ni < 4; ++ni) {
                acc[mi][ni] = __builtin_amdgcn_mfma_f32_16x16x32_bf16(ah, bh[ni], acc[mi][ni], 0, 0, 0);
                acc[mi][ni] = __builtin_amdgcn_mfma_f32_16x16x32_bf16(al, bh[ni], acc[mi][ni], 0, 0, 0);
                acc[mi][ni] = __builtin_amdgcn_mfma_f32_16x16x32_bf16(ah, bl[ni], acc[mi][ni], 0, 0, 0);
            }
        }
    };

    STAGE(0, 0);
    for (int t = 0; t < KSTEPS - 1; ++t) {
        STAGE((t + 1) & 1, t + 1);                       // 8 loads in flight for t+1
        asm volatile("s_waitcnt vmcnt(8)" ::: "memory"); // tile t's 8 loads done
        __builtin_amdgcn_s_barrier();
        COMPUTE(t & 1);
        asm volatile("s_waitcnt lgkmcnt(0)" ::: "memory");
        __builtin_amdgcn_s_barrier();                    // reads done before overwrite
    }
    asm volatile("s_waitcnt vmcnt(0)" ::: "memory");
    __builtin_amdgcn_s_barrier();
    COMPUTE((KSTEPS - 1) & 1);

    // ---- epilogue: C/D layout col=lane&15, row=(lane>>4)*4+reg ----
    const int orow = m0 + wr * 128 + (lane >> 4) * 4;
    const int ocol = n0 + wcn * 64 + fr;
    #pragma unroll
    for (int mi = 0; mi < 8; ++mi)
        #pragma unroll
        for (int ni = 0; ni < 4; ++ni)
            #pragma unroll
            for (int rr = 0; rr < 4; ++rr) {
                float v = acc[mi][ni][rr];
                if (SIG) v = 1.f / (1.f + expf(-v));
                Y[(size_t)(orow + mi * 16 + rr) * C_ + ocol + ni * 16] = v;
            }
}

// ---------------- WKV recurrence: writes r*rwkv as bf16 hi/lo planes -----
__global__ __launch_bounds__(128) void wkv_kernel(const float* __restrict__ k,
                                                  const float* __restrict__ v,
                                                  const float* __restrict__ r,
                                                  const float* __restrict__ time_decay,
                                                  const float* __restrict__ time_first,
                                                  unsigned short* __restrict__ yhi,
                                                  unsigned short* __restrict__ ylo) {
    const int c = blockIdx.x * 128 + threadIdx.x;
    const int b = blockIdx.y;
    const float decay = 1.f / (1.f + expf(-time_decay[c]));
    const float first = expf(time_first[c]);

    size_t base = (size_t)b * T_ * C_ + c;
    float state = 0.f;
    #pragma unroll 4
    for (int t = 0; t < T_; ++t) {
        const float kt = k[base];
        const float vt = v[base];
        const float rt = r[base];
        state = state * decay + kt;
        const float y = rt * ((state * first + kt) * vt);
        unsigned short h, l;
        split_bf16(y, h, l);
        yhi[base] = h;
        ylo[base] = l;
        base += C_;
    }
}

// ---------------- launch ----------------
extern "C" void kernel_launch(void* const* d_in, const int* in_sizes, int n_in,
                              void* d_out, int out_size, void* d_ws, size_t ws_size,
                              hipStream_t stream) {
    const float* x          = (const float*)d_in[0];
    const float* ln_w       = (const float*)d_in[1];
    const float* ln_b       = (const float*)d_in[2];
    const float* mix_k      = (const float*)d_in[3];
    const float* mix_v      = (const float*)d_in[4];
    const float* mix_r      = (const float*)d_in[5];
    const float* time_decay = (const float*)d_in[6];
    const float* time_first = (const float*)d_in[7];
    const float* Wk         = (const float*)d_in[8];
    const float* Wv         = (const float*)d_in[9];
    const float* Wr         = (const float*)d_in[10];
    const float* Wo         = (const float*)d_in[11];
    float* out = (float*)d_out;

    // ws (208.8 MB): xt/vb 64MB | A planes hi+lo 64MB | kb 64MB | W planes 16.8MB
    const size_t planeElems = (size_t)M_ * C_;
    float* xt = (float*)d_ws;                                   // later reused as vb
    unsigned short* aphi = (unsigned short*)(xt + planeElems);
    unsigned short* aplo = aphi + planeElems;
    float* kb = (float*)(aplo + planeElems);
    unsigned short* whi = (unsigned short*)(kb + planeElems);
    unsigned short* wlo = whi + (size_t)C_ * C_;
    float* vb = xt;            // alias: xt dead after last mixsplit
    float* rb = out;           // r lives in d_out until consumed by WKV

    const int msBlocks = (int)(planeElems / 4) / 256;   // 16384
    const int wcBlocks = (C_ * C_ / 4) / 256;           // 4096

    // 1. LayerNorm
    ln_kernel<<<M_, 256, 0, stream>>>(x, ln_w, ln_b, xt);

    // 2. r projection first (output -> d_out)
    mixsplit_kernel<<<msBlocks, 256, 0, stream>>>(xt, mix_r, aphi, aplo);
    wconv_kernel<<<wcBlocks, 256, 0, stream>>>(Wr, whi, wlo);
    gemm_mfma<true><<<256, 512, 0, stream>>>(aphi, aplo, whi, wlo, rb);

    // 3. k projection
    mixsplit_kernel<<<msBlocks, 256, 0, stream>>>(xt, mix_k, aphi, aplo);
    wconv_kernel<<<wcBlocks, 256, 0, stream>>>(Wk, whi, wlo);
    gemm_mfma<false><<<256, 512, 0, stream>>>(aphi, aplo, whi, wlo, kb);

    // 4. v projection (last reader of xt; output overwrites xt region)
    mixsplit_kernel<<<msBlocks, 256, 0, stream>>>(xt, mix_v, aphi, aplo);
    wconv_kernel<<<wcBlocks, 256, 0, stream>>>(Wv, whi, wlo);
    gemm_mfma<false><<<256, 512, 0, stream>>>(aphi, aplo, whi, wlo, vb);

    // 5. WKV recurrence -> split planes (A-plane region is free now)
    wkv_kernel<<<dim3(C_ / 128, B_), 128, 0, stream>>>(kb, vb, rb, time_decay, time_first,
                                                       aphi, aplo);

    // 6. output projection
    wconv_kernel<<<wcBlocks, 256, 0, stream>>>(Wo, whi, wlo);
    gemm_mfma<false><<<256, 512, 0, stream>>>(aphi, aplo, whi, wlo, out);
}

// Round 5
// 811.742 us; speedup vs baseline: 5.0610x; 1.5610x over previous
//
#include <hip/hip_runtime.h>
#include <math.h>

// RWKV6 block on MI355X. fp32 problem; GEMMs via split-bf16 (hi/lo) x3 MFMA emulation.
// B=4, T=2048, C=2048. WKV recurrence via chunked parallel scan (32 chunks of 64).
constexpr int B_ = 4;
constexpr int T_ = 2048;
constexpr int C_ = 2048;
constexpr int M_ = B_ * T_;          // 8192 rows
constexpr float EPS_ = 1e-5f;
constexpr int KSTEPS = C_ / 32;      // 64
constexpr int NCH = 32;              // scan chunks
constexpr int CHL = T_ / NCH;        // 64 steps/chunk

typedef __attribute__((ext_vector_type(8))) short short8;   // bf16x8 MFMA operand
typedef __attribute__((ext_vector_type(4))) float f32x4;    // MFMA acc

__device__ __forceinline__ unsigned short rne_bf16(float x) {
    unsigned u = __float_as_uint(x);
    unsigned r = u + 0x7FFFu + ((u >> 16) & 1u);
    return (unsigned short)(r >> 16);
}
__device__ __forceinline__ void split_bf16(float x, unsigned short& hi, unsigned short& lo) {
    hi = rne_bf16(x);
    lo = rne_bf16(x - __uint_as_float((unsigned)hi << 16));
}

// ---------------- LayerNorm: one block per (b,t) row ----------------
__global__ __launch_bounds__(256) void ln_kernel(const float* __restrict__ x,
                                                 const float* __restrict__ w,
                                                 const float* __restrict__ bias,
                                                 float* __restrict__ xt) {
    const int row = blockIdx.x;
    const float* xr = x + (size_t)row * C_;
    const int tid = threadIdx.x;

    float4 v0 = ((const float4*)xr)[tid];
    float4 v1 = ((const float4*)xr)[tid + 256];

    float s = v0.x + v0.y + v0.z + v0.w + v1.x + v1.y + v1.z + v1.w;
    float q = v0.x*v0.x + v0.y*v0.y + v0.z*v0.z + v0.w*v0.w
            + v1.x*v1.x + v1.y*v1.y + v1.z*v1.z + v1.w*v1.w;

    #pragma unroll
    for (int off = 32; off > 0; off >>= 1) {
        s += __shfl_down(s, off, 64);
        q += __shfl_down(q, off, 64);
    }
    __shared__ float red[10];
    const int wid = tid >> 6, lane = tid & 63;
    if (lane == 0) { red[wid * 2] = s; red[wid * 2 + 1] = q; }
    __syncthreads();
    if (tid == 0) {
        float ts = 0.f, tq = 0.f;
        #pragma unroll
        for (int i = 0; i < 4; ++i) { ts += red[i * 2]; tq += red[i * 2 + 1]; }
        const float mu = ts / (float)C_;
        const float var = tq / (float)C_ - mu * mu;
        red[8] = mu;
        red[9] = rsqrtf(var + EPS_);
    }
    __syncthreads();
    const float mu = red[8], rstd = red[9];

    float4 w0 = ((const float4*)w)[tid];
    float4 w1 = ((const float4*)w)[tid + 256];
    float4 b0 = ((const float4*)bias)[tid];
    float4 b1 = ((const float4*)bias)[tid + 256];

    float4 o0, o1;
    o0.x = (v0.x - mu) * rstd * w0.x + b0.x;
    o0.y = (v0.y - mu) * rstd * w0.y + b0.y;
    o0.z = (v0.z - mu) * rstd * w0.z + b0.z;
    o0.w = (v0.w - mu) * rstd * w0.w + b0.w;
    o1.x = (v1.x - mu) * rstd * w1.x + b1.x;
    o1.y = (v1.y - mu) * rstd * w1.y + b1.y;
    o1.z = (v1.z - mu) * rstd * w1.z + b1.z;
    o1.w = (v1.w - mu) * rstd * w1.w + b1.w;

    float* outr = xt + (size_t)row * C_;
    ((float4*)outr)[tid] = o0;
    ((float4*)outr)[tid + 256] = o1;
}

// ---------------- time-mix + split to bf16 hi/lo planes ----------------
__global__ __launch_bounds__(256) void mixsplit_kernel(const float* __restrict__ xt,
                                                       const float* __restrict__ mix,
                                                       unsigned short* __restrict__ hi,
                                                       unsigned short* __restrict__ lo) {
    const int i = blockIdx.x * 256 + threadIdx.x;   // over M_*C_/4 float4s
    const int m = i >> 9;                           // C_/4 = 512
    const int c4 = i & 511;
    const float4 cur = ((const float4*)xt)[i];
    const float4 mx = ((const float4*)mix)[c4];
    float4 prev = make_float4(0.f, 0.f, 0.f, 0.f);
    if ((m & (T_ - 1)) != 0) prev = ((const float4*)xt)[i - 512];
    float4 a;
    a.x = prev.x + (cur.x - prev.x) * mx.x;
    a.y = prev.y + (cur.y - prev.y) * mx.y;
    a.z = prev.z + (cur.z - prev.z) * mx.z;
    a.w = prev.w + (cur.w - prev.w) * mx.w;
    ushort4 h, l;
    split_bf16(a.x, h.x, l.x);
    split_bf16(a.y, h.y, l.y);
    split_bf16(a.z, h.z, l.z);
    split_bf16(a.w, h.w, l.w);
    ((ushort4*)hi)[i] = h;
    ((ushort4*)lo)[i] = l;
}

// ---------------- W fp32 -> (hi, lo) bf16 planes ----------------
__global__ __launch_bounds__(256) void wconv_kernel(const float* __restrict__ W,
                                                    unsigned short* __restrict__ hi,
                                                    unsigned short* __restrict__ lo) {
    const int i = blockIdx.x * 256 + threadIdx.x;   // over C_*C_/4 float4s
    float4 w = ((const float4*)W)[i];
    ushort4 h, l;
    split_bf16(w.x, h.x, l.x);
    split_bf16(w.y, h.y, l.y);
    split_bf16(w.z, h.z, l.z);
    split_bf16(w.w, h.w, l.w);
    ((ushort4*)hi)[i] = h;
    ((ushort4*)lo)[i] = l;
}

// ---------------- MFMA GEMM: Y[m,n] = sum_k A[m,k] * W[n,k] --------------
// A,W pre-split bf16 hi/lo planes. acc += Ah*Wh + Al*Wh + Ah*Wl.
// 256x256 tile, BK=32, 512 threads (8 waves, 2Mx4N), 128KB LDS double-buffer.
// LDS per region: 256 rows x 8 slots of 16B; physical slot p = s ^ (row&7).
// global_load_lds fills LDS linearly; per-lane GLOBAL source applies the
// inverse swizzle (both-sides-or-neither).
template <bool SIG>
__global__ __launch_bounds__(512, 2) void gemm_mfma(const unsigned short* __restrict__ Ahi,
                                                    const unsigned short* __restrict__ Alo,
                                                    const unsigned short* __restrict__ Whi,
                                                    const unsigned short* __restrict__ Wlo,
                                                    float* __restrict__ Y) {
    __shared__ unsigned short lds[2][2][256 * 64];

    const int tid = threadIdx.x;
    const int lane = tid & 63;
    const int wid = tid >> 6;          // 0..7
    const int wr = wid >> 2;           // 0..1  (M half: 128 rows)
    const int wcn = wid & 3;           // 0..3  (N quarter: 64 cols)

    // XCD-chunked block swizzle: 256 blocks, 8 XCDs, 32/XCD
    const int bid = blockIdx.x;
    const int swz = (bid & 7) * 32 + (bid >> 3);
    const int m0 = (swz >> 3) * 256;
    const int n0 = (swz & 7) * 256;

    const unsigned short* gA[4];
    const unsigned short* gB[4];
    #pragma unroll
    for (int j = 0; j < 4; ++j) {
        const int ci = j * 512 + tid;
        const int r = ci >> 3, p = ci & 7;
        const int s = p ^ (r & 7);
        const int pl = s >> 2, ks = s & 3;
        gA[j] = (pl ? Alo : Ahi) + (size_t)(m0 + r) * C_ + ks * 8;
        gB[j] = (pl ? Wlo : Whi) + (size_t)(n0 + r) * C_ + ks * 8;
    }
    const int stage_off = wid * 512;

    const int fr = lane & 15;
    const int kg = lane >> 4;
    const int pH = (kg + 0) ^ (fr & 7);
    const int pL = (kg + 4) ^ (fr & 7);
    const int baseA0 = (wr * 128 + fr) * 64 + pH * 8;
    const int baseA1 = (wr * 128 + fr) * 64 + pL * 8;
    const int baseB0 = (wcn * 64 + fr) * 64 + pH * 8;
    const int baseB1 = (wcn * 64 + fr) * 64 + pL * 8;

    f32x4 acc[8][4] = {};

    auto STAGE = [&](int buf, int t) {
        const int ko = t * 32;
        #pragma unroll
        for (int j = 0; j < 4; ++j)
            __builtin_amdgcn_global_load_lds(
                (const __attribute__((address_space(1))) unsigned int*)(gA[j] + ko),
                (__attribute__((address_space(3))) unsigned int*)&lds[buf][0][j * 4096 + stage_off],
                16, 0, 0);
        #pragma unroll
        for (int j = 0; j < 4; ++j)
            __builtin_amdgcn_global_load_lds(
                (const __attribute__((address_space(1))) unsigned int*)(gB[j] + ko),
                (__attribute__((address_space(3))) unsigned int*)&lds[buf][1][j * 4096 + stage_off],
                16, 0, 0);
    };

    auto COMPUTE = [&](int buf) {
        const unsigned short* LA = lds[buf][0];
        const unsigned short* LB = lds[buf][1];
        short8 bh[4], bl[4];
        #pragma unroll
        for (int ni = 0; ni < 4; ++ni) {
            bh[ni] = *(const short8*)&LB[baseB0 + ni * 1024];
            bl[ni] = *(const short8*)&LB[baseB1 + ni * 1024];
        }
        #pragma unroll
        for (int mi = 0; mi < 8; ++mi) {
            const short8 ah = *(const short8*)&LA[baseA0 + mi * 1024];
            const short8 al = *(const short8*)&LA[baseA1 + mi * 1024];
            #pragma unroll
            for (int ni = 0; ni < 4; ++ni) {
                acc[mi][ni] = __builtin_amdgcn_mfma_f32_16x16x32_bf16(ah, bh[ni], acc[mi][ni], 0, 0, 0);
                acc[mi][ni] = __builtin_amdgcn_mfma_f32_16x16x32_bf16(al, bh[ni], acc[mi][ni], 0, 0, 0);
                acc[mi][ni] = __builtin_amdgcn_mfma_f32_16x16x32_bf16(ah, bl[ni], acc[mi][ni], 0, 0, 0);
            }
        }
    };

    STAGE(0, 0);
    for (int t = 0; t < KSTEPS - 1; ++t) {
        STAGE((t + 1) & 1, t + 1);
        asm volatile("s_waitcnt vmcnt(8)" ::: "memory");
        __builtin_amdgcn_s_barrier();
        COMPUTE(t & 1);
        asm volatile("s_waitcnt lgkmcnt(0)" ::: "memory");
        __builtin_amdgcn_s_barrier();
    }
    asm volatile("s_waitcnt vmcnt(0)" ::: "memory");
    __builtin_amdgcn_s_barrier();
    COMPUTE((KSTEPS - 1) & 1);

    const int orow = m0 + wr * 128 + (lane >> 4) * 4;
    const int ocol = n0 + wcn * 64 + fr;
    #pragma unroll
    for (int mi = 0; mi < 8; ++mi)
        #pragma unroll
        for (int ni = 0; ni < 4; ++ni)
            #pragma unroll
            for (int rr = 0; rr < 4; ++rr) {
                float v = acc[mi][ni][rr];
                if (SIG) v = 1.f / (1.f + expf(-v));
                Y[(size_t)(orow + mi * 16 + rr) * C_ + ocol + ni * 16] = v;
            }
}

// ---------------- WKV chunked scan, pass 1: per-chunk local end state ----
// 2 channels per thread (float2 loads). chend[b][j][c] = local scan end.
__global__ __launch_bounds__(256) void wkv_scan1(const float* __restrict__ k,
                                                 const float* __restrict__ time_decay,
                                                 float* __restrict__ chend) {
    const int c0 = (blockIdx.x * 256 + threadIdx.x) * 2;
    const int j = blockIdx.y;
    const int b = blockIdx.z;
    const float2 td = *(const float2*)&time_decay[c0];
    const float d0 = 1.f / (1.f + expf(-td.x));
    const float d1 = 1.f / (1.f + expf(-td.y));
    size_t base = ((size_t)b * T_ + (size_t)j * CHL) * C_ + c0;
    float s0 = 0.f, s1 = 0.f;
    #pragma unroll 8
    for (int t = 0; t < CHL; ++t) {
        const float2 kt = *(const float2*)&k[base];
        s0 = s0 * d0 + kt.x;
        s1 = s1 * d1 + kt.y;
        base += C_;
    }
    *(float2*)&chend[((size_t)b * NCH + j) * C_ + c0] = make_float2(s0, s1);
}

// ---------------- WKV chunked scan, pass 2: carry-in + rescan + fuse -----
// carry = sum_{i<j} d^(CHL*(j-1-i)) * chend[i]; then exact sequential rescan
// of the chunk, fused with y = r*((s*first+k)*v) and bf16 hi/lo split-write.
__global__ __launch_bounds__(256) void wkv_scan2(const float* __restrict__ k,
                                                 const float* __restrict__ v,
                                                 const float* __restrict__ r,
                                                 const float* __restrict__ time_decay,
                                                 const float* __restrict__ time_first,
                                                 const float* __restrict__ chend,
                                                 unsigned short* __restrict__ yhi,
                                                 unsigned short* __restrict__ ylo) {
    const int c0 = (blockIdx.x * 256 + threadIdx.x) * 2;
    const int j = blockIdx.y;
    const int b = blockIdx.z;
    const float2 td = *(const float2*)&time_decay[c0];
    const float2 tf = *(const float2*)&time_first[c0];
    const float d0 = 1.f / (1.f + expf(-td.x));
    const float d1 = 1.f / (1.f + expf(-td.y));
    const float f0 = expf(tf.x);
    const float f1 = expf(tf.y);

    float dL0 = d0, dL1 = d1;           // d^CHL, CHL=64 -> 6 squarings
    #pragma unroll
    for (int i = 0; i < 6; ++i) { dL0 *= dL0; dL1 *= dL1; }

    float s0 = 0.f, s1 = 0.f;
    for (int i = 0; i < j; ++i) {
        const float2 e = *(const float2*)&chend[((size_t)b * NCH + i) * C_ + c0];
        s0 = s0 * dL0 + e.x;
        s1 = s1 * dL1 + e.y;
    }

    size_t base = ((size_t)b * T_ + (size_t)j * CHL) * C_ + c0;
    #pragma unroll 4
    for (int t = 0; t < CHL; ++t) {
        const float2 kt = *(const float2*)&k[base];
        const float2 vt = *(const float2*)&v[base];
        const float2 rt = *(const float2*)&r[base];
        s0 = s0 * d0 + kt.x;
        s1 = s1 * d1 + kt.y;
        const float y0 = rt.x * ((s0 * f0 + kt.x) * vt.x);
        const float y1 = rt.y * ((s1 * f1 + kt.y) * vt.y);
        unsigned short h0, l0, h1, l1;
        split_bf16(y0, h0, l0);
        split_bf16(y1, h1, l1);
        ushort2 ph; ph.x = h0; ph.y = h1;
        ushort2 pl; pl.x = l0; pl.y = l1;
        *(ushort2*)&yhi[base] = ph;
        *(ushort2*)&ylo[base] = pl;
        base += C_;
    }
}

// ---------------- launch ----------------
extern "C" void kernel_launch(void* const* d_in, const int* in_sizes, int n_in,
                              void* d_out, int out_size, void* d_ws, size_t ws_size,
                              hipStream_t stream) {
    const float* x          = (const float*)d_in[0];
    const float* ln_w       = (const float*)d_in[1];
    const float* ln_b       = (const float*)d_in[2];
    const float* mix_k      = (const float*)d_in[3];
    const float* mix_v      = (const float*)d_in[4];
    const float* mix_r      = (const float*)d_in[5];
    const float* time_decay = (const float*)d_in[6];
    const float* time_first = (const float*)d_in[7];
    const float* Wk         = (const float*)d_in[8];
    const float* Wv         = (const float*)d_in[9];
    const float* Wr         = (const float*)d_in[10];
    const float* Wo         = (const float*)d_in[11];
    float* out = (float*)d_out;

    // ws (211.8 MB): xt/vb 64MB | A planes hi+lo 67MB | kb 64MB | W planes 16.8MB
    const size_t planeElems = (size_t)M_ * C_;
    float* xt = (float*)d_ws;                                   // later reused as vb
    unsigned short* aphi = (unsigned short*)(xt + planeElems);
    unsigned short* aplo = aphi + planeElems;
    float* kb = (float*)(aplo + planeElems);
    unsigned short* whi = (unsigned short*)(kb + planeElems);
    unsigned short* wlo = whi + (size_t)C_ * C_;
    float* vb = xt;            // alias: xt dead after last mixsplit
    float* rb = out;           // r lives in d_out until consumed by WKV
    // chend (1MB) aliases the W-plane region: dead between v-GEMM and Wo wconv
    float* chend = (float*)whi;

    const int msBlocks = (int)(planeElems / 4) / 256;   // 16384
    const int wcBlocks = (C_ * C_ / 4) / 256;           // 4096
    const dim3 wkvGrid(C_ / 512, NCH, B_);

    // 1. LayerNorm
    ln_kernel<<<M_, 256, 0, stream>>>(x, ln_w, ln_b, xt);

    // 2. r projection first (output -> d_out)
    mixsplit_kernel<<<msBlocks, 256, 0, stream>>>(xt, mix_r, aphi, aplo);
    wconv_kernel<<<wcBlocks, 256, 0, stream>>>(Wr, whi, wlo);
    gemm_mfma<true><<<256, 512, 0, stream>>>(aphi, aplo, whi, wlo, rb);

    // 3. k projection
    mixsplit_kernel<<<msBlocks, 256, 0, stream>>>(xt, mix_k, aphi, aplo);
    wconv_kernel<<<wcBlocks, 256, 0, stream>>>(Wk, whi, wlo);
    gemm_mfma<false><<<256, 512, 0, stream>>>(aphi, aplo, whi, wlo, kb);

    // 4. v projection (last reader of xt; output overwrites xt region)
    mixsplit_kernel<<<msBlocks, 256, 0, stream>>>(xt, mix_v, aphi, aplo);
    wconv_kernel<<<wcBlocks, 256, 0, stream>>>(Wv, whi, wlo);
    gemm_mfma<false><<<256, 512, 0, stream>>>(aphi, aplo, whi, wlo, vb);

    // 5. WKV chunked scan -> split planes (A-plane region free; chend in W region)
    wkv_scan1<<<wkvGrid, 256, 0, stream>>>(kb, time_decay, chend);
    wkv_scan2<<<wkvGrid, 256, 0, stream>>>(kb, vb, rb, time_decay, time_first, chend,
                                           aphi, aplo);

    // 6. output projection (wconv overwrites chend only after scan2 done)
    wconv_kernel<<<wcBlocks, 256, 0, stream>>>(Wo, whi, wlo);
    gemm_mfma<false><<<256, 512, 0, stream>>>(aphi, aplo, whi, wlo, out);
}

// Round 6
// 801.622 us; speedup vs baseline: 5.1248x; 1.0126x over previous
//
#include <hip/hip_runtime.h>
#include <math.h>

// RWKV6 block on MI355X. fp32 problem; GEMMs via split-bf16 (hi/lo) x3 MFMA emulation.
// B=4, T=2048, C=2048. WKV recurrence via chunked parallel scan (32 chunks of 64).
// GEMM: 256x256 tile, 8 waves, XOR-swizzled LDS, 4-phase interleaved K-loop
// with counted vmcnt + setprio (T2+T3+T4+T5).
constexpr int B_ = 4;
constexpr int T_ = 2048;
constexpr int C_ = 2048;
constexpr int M_ = B_ * T_;          // 8192 rows
constexpr float EPS_ = 1e-5f;
constexpr int KSTEPS = C_ / 32;      // 64
constexpr int NCH = 32;              // scan chunks
constexpr int CHL = T_ / NCH;        // 64 steps/chunk

typedef __attribute__((ext_vector_type(8))) short short8;   // bf16x8 MFMA operand
typedef __attribute__((ext_vector_type(4))) float f32x4;    // MFMA acc

__device__ __forceinline__ unsigned short rne_bf16(float x) {
    unsigned u = __float_as_uint(x);
    unsigned r = u + 0x7FFFu + ((u >> 16) & 1u);
    return (unsigned short)(r >> 16);
}
__device__ __forceinline__ void split_bf16(float x, unsigned short& hi, unsigned short& lo) {
    hi = rne_bf16(x);
    lo = rne_bf16(x - __uint_as_float((unsigned)hi << 16));
}

// ---------------- LayerNorm: one block per (b,t) row ----------------
__global__ __launch_bounds__(256) void ln_kernel(const float* __restrict__ x,
                                                 const float* __restrict__ w,
                                                 const float* __restrict__ bias,
                                                 float* __restrict__ xt) {
    const int row = blockIdx.x;
    const float* xr = x + (size_t)row * C_;
    const int tid = threadIdx.x;

    float4 v0 = ((const float4*)xr)[tid];
    float4 v1 = ((const float4*)xr)[tid + 256];

    float s = v0.x + v0.y + v0.z + v0.w + v1.x + v1.y + v1.z + v1.w;
    float q = v0.x*v0.x + v0.y*v0.y + v0.z*v0.z + v0.w*v0.w
            + v1.x*v1.x + v1.y*v1.y + v1.z*v1.z + v1.w*v1.w;

    #pragma unroll
    for (int off = 32; off > 0; off >>= 1) {
        s += __shfl_down(s, off, 64);
        q += __shfl_down(q, off, 64);
    }
    __shared__ float red[10];
    const int wid = tid >> 6, lane = tid & 63;
    if (lane == 0) { red[wid * 2] = s; red[wid * 2 + 1] = q; }
    __syncthreads();
    if (tid == 0) {
        float ts = 0.f, tq = 0.f;
        #pragma unroll
        for (int i = 0; i < 4; ++i) { ts += red[i * 2]; tq += red[i * 2 + 1]; }
        const float mu = ts / (float)C_;
        const float var = tq / (float)C_ - mu * mu;
        red[8] = mu;
        red[9] = rsqrtf(var + EPS_);
    }
    __syncthreads();
    const float mu = red[8], rstd = red[9];

    float4 w0 = ((const float4*)w)[tid];
    float4 w1 = ((const float4*)w)[tid + 256];
    float4 b0 = ((const float4*)bias)[tid];
    float4 b1 = ((const float4*)bias)[tid + 256];

    float4 o0, o1;
    o0.x = (v0.x - mu) * rstd * w0.x + b0.x;
    o0.y = (v0.y - mu) * rstd * w0.y + b0.y;
    o0.z = (v0.z - mu) * rstd * w0.z + b0.z;
    o0.w = (v0.w - mu) * rstd * w0.w + b0.w;
    o1.x = (v1.x - mu) * rstd * w1.x + b1.x;
    o1.y = (v1.y - mu) * rstd * w1.y + b1.y;
    o1.z = (v1.z - mu) * rstd * w1.z + b1.z;
    o1.w = (v1.w - mu) * rstd * w1.w + b1.w;

    float* outr = xt + (size_t)row * C_;
    ((float4*)outr)[tid] = o0;
    ((float4*)outr)[tid + 256] = o1;
}

// ---------------- time-mix + split to bf16 hi/lo planes ----------------
__global__ __launch_bounds__(256) void mixsplit_kernel(const float* __restrict__ xt,
                                                       const float* __restrict__ mix,
                                                       unsigned short* __restrict__ hi,
                                                       unsigned short* __restrict__ lo) {
    const int i = blockIdx.x * 256 + threadIdx.x;   // over M_*C_/4 float4s
    const int m = i >> 9;                           // C_/4 = 512
    const int c4 = i & 511;
    const float4 cur = ((const float4*)xt)[i];
    const float4 mx = ((const float4*)mix)[c4];
    float4 prev = make_float4(0.f, 0.f, 0.f, 0.f);
    if ((m & (T_ - 1)) != 0) prev = ((const float4*)xt)[i - 512];
    float4 a;
    a.x = prev.x + (cur.x - prev.x) * mx.x;
    a.y = prev.y + (cur.y - prev.y) * mx.y;
    a.z = prev.z + (cur.z - prev.z) * mx.z;
    a.w = prev.w + (cur.w - prev.w) * mx.w;
    ushort4 h, l;
    split_bf16(a.x, h.x, l.x);
    split_bf16(a.y, h.y, l.y);
    split_bf16(a.z, h.z, l.z);
    split_bf16(a.w, h.w, l.w);
    ((ushort4*)hi)[i] = h;
    ((ushort4*)lo)[i] = l;
}

// ---------------- W fp32 -> (hi, lo) bf16 planes ----------------
__global__ __launch_bounds__(256) void wconv_kernel(const float* __restrict__ W,
                                                    unsigned short* __restrict__ hi,
                                                    unsigned short* __restrict__ lo) {
    const int i = blockIdx.x * 256 + threadIdx.x;   // over C_*C_/4 float4s
    float4 w = ((const float4*)W)[i];
    ushort4 h, l;
    split_bf16(w.x, h.x, l.x);
    split_bf16(w.y, h.y, l.y);
    split_bf16(w.z, h.z, l.z);
    split_bf16(w.w, h.w, l.w);
    ((ushort4*)hi)[i] = h;
    ((ushort4*)lo)[i] = l;
}

// ---------------- MFMA GEMM: Y[m,n] = sum_k A[m,k] * W[n,k] --------------
// acc += Ah*Wh + Al*Wh + Ah*Wl. 256x256 tile, BK=32, 512 threads (8 waves,
// 2Mx4N). 128KB LDS double-buffer; per region 256 rows x 8 slots of 16B,
// physical slot p = s ^ (row&7) (conflict-free); global_load_lds dest linear,
// per-lane GLOBAL source pre-applies the inverse swizzle.
// K-loop: 4 phases per K-step (one mi-pair each, 24 MFMA), each phase issues
// 2 of the next tile's 8 loads; vmcnt counted (never 0 mid-loop); setprio
// around MFMA clusters.
template <bool SIG>
__global__ __launch_bounds__(512, 2) void gemm_mfma(const unsigned short* __restrict__ Ahi,
                                                    const unsigned short* __restrict__ Alo,
                                                    const unsigned short* __restrict__ Whi,
                                                    const unsigned short* __restrict__ Wlo,
                                                    float* __restrict__ Y) {
    __shared__ unsigned short lds[2][2][256 * 64];

    const int tid = threadIdx.x;
    const int lane = tid & 63;
    const int wid = tid >> 6;          // 0..7
    const int wr = wid >> 2;           // 0..1  (M half: 128 rows)
    const int wcn = wid & 3;           // 0..3  (N quarter: 64 cols)

    // XCD-chunked block swizzle: 256 blocks, 8 XCDs, 32/XCD
    const int bid = blockIdx.x;
    const int swz = (bid & 7) * 32 + (bid >> 3);
    const int m0 = (swz >> 3) * 256;
    const int n0 = (swz & 7) * 256;

    const unsigned short* gA[4];
    const unsigned short* gB[4];
    #pragma unroll
    for (int j = 0; j < 4; ++j) {
        const int ci = j * 512 + tid;
        const int r = ci >> 3, p = ci & 7;
        const int s = p ^ (r & 7);
        const int pl = s >> 2, ks = s & 3;
        gA[j] = (pl ? Alo : Ahi) + (size_t)(m0 + r) * C_ + ks * 8;
        gB[j] = (pl ? Wlo : Whi) + (size_t)(n0 + r) * C_ + ks * 8;
    }
    const int stage_off = wid * 512;

    const int fr = lane & 15;
    const int kg = lane >> 4;
    const int pH = (kg + 0) ^ (fr & 7);
    const int pL = (kg + 4) ^ (fr & 7);
    const int baseA0 = (wr * 128 + fr) * 64 + pH * 8;
    const int baseA1 = (wr * 128 + fr) * 64 + pL * 8;
    const int baseB0 = (wcn * 64 + fr) * 64 + pH * 8;
    const int baseB1 = (wcn * 64 + fr) * 64 + pL * 8;

    f32x4 acc[8][4] = {};

    auto ISSUE = [&](int buf, int t, int j) {
        const int ko = t * 32;
        __builtin_amdgcn_global_load_lds(
            (const __attribute__((address_space(1))) unsigned int*)(gA[j] + ko),
            (__attribute__((address_space(3))) unsigned int*)&lds[buf][0][j * 4096 + stage_off],
            16, 0, 0);
        __builtin_amdgcn_global_load_lds(
            (const __attribute__((address_space(1))) unsigned int*)(gB[j] + ko),
            (__attribute__((address_space(3))) unsigned int*)&lds[buf][1][j * 4096 + stage_off],
            16, 0, 0);
    };

    // prologue: stage tile 0 (8 loads/thread)
    #pragma unroll
    for (int j = 0; j < 4; ++j) ISSUE(0, 0, j);

    for (int t = 0; t < KSTEPS; ++t) {
        const int cur = t & 1, nxt = cur ^ 1;
        const bool last = (t == KSTEPS - 1);
        const unsigned short* LA = lds[cur][0];
        const unsigned short* LB = lds[cur][1];

        short8 bh[4], bl[4];

        // ---------- phase 0 (mi 0,1): validate buf cur, read B frags ----------
        if (!last) {
            ISSUE(nxt, t + 1, 0);
            asm volatile("s_waitcnt vmcnt(2)" ::: "memory");  // tile t's 8 done, 2 in flight
        } else {
            asm volatile("s_waitcnt vmcnt(0)" ::: "memory");
        }
        __builtin_amdgcn_s_barrier();
        #pragma unroll
        for (int ni = 0; ni < 4; ++ni) {
            bh[ni] = *(const short8*)&LB[baseB0 + ni * 1024];
            bl[ni] = *(const short8*)&LB[baseB1 + ni * 1024];
        }
        {
            const short8 a0h = *(const short8*)&LA[baseA0 + 0 * 1024];
            const short8 a0l = *(const short8*)&LA[baseA1 + 0 * 1024];
            const short8 a1h = *(const short8*)&LA[baseA0 + 1 * 1024];
            const short8 a1l = *(const short8*)&LA[baseA1 + 1 * 1024];
            asm volatile("s_waitcnt lgkmcnt(0)" ::: "memory");
            __builtin_amdgcn_s_setprio(1);
            #pragma unroll
            for (int ni = 0; ni < 4; ++ni) {
                acc[0][ni] = __builtin_amdgcn_mfma_f32_16x16x32_bf16(a0h, bh[ni], acc[0][ni], 0, 0, 0);
                acc[0][ni] = __builtin_amdgcn_mfma_f32_16x16x32_bf16(a0l, bh[ni], acc[0][ni], 0, 0, 0);
                acc[0][ni] = __builtin_amdgcn_mfma_f32_16x16x32_bf16(a0h, bl[ni], acc[0][ni], 0, 0, 0);
                acc[1][ni] = __builtin_amdgcn_mfma_f32_16x16x32_bf16(a1h, bh[ni], acc[1][ni], 0, 0, 0);
                acc[1][ni] = __builtin_amdgcn_mfma_f32_16x16x32_bf16(a1l, bh[ni], acc[1][ni], 0, 0, 0);
                acc[1][ni] = __builtin_amdgcn_mfma_f32_16x16x32_bf16(a1h, bl[ni], acc[1][ni], 0, 0, 0);
            }
            __builtin_amdgcn_s_setprio(0);
        }
        __builtin_amdgcn_s_barrier();

        // ---------- phases 1..3 (mi-pairs 2-3, 4-5, 6-7) ----------
        #pragma unroll
        for (int p = 1; p < 4; ++p) {
            const int mi0 = 2 * p;
            const short8 a0h = *(const short8*)&LA[baseA0 + mi0 * 1024];
            const short8 a0l = *(const short8*)&LA[baseA1 + mi0 * 1024];
            const short8 a1h = *(const short8*)&LA[baseA0 + (mi0 + 1) * 1024];
            const short8 a1l = *(const short8*)&LA[baseA1 + (mi0 + 1) * 1024];
            if (!last) ISSUE(nxt, t + 1, p);
            __builtin_amdgcn_s_barrier();
            asm volatile("s_waitcnt lgkmcnt(0)" ::: "memory");
            __builtin_amdgcn_s_setprio(1);
            #pragma unroll
            for (int ni = 0; ni < 4; ++ni) {
                acc[mi0][ni]     = __builtin_amdgcn_mfma_f32_16x16x32_bf16(a0h, bh[ni], acc[mi0][ni], 0, 0, 0);
                acc[mi0][ni]     = __builtin_amdgcn_mfma_f32_16x16x32_bf16(a0l, bh[ni], acc[mi0][ni], 0, 0, 0);
                acc[mi0][ni]     = __builtin_amdgcn_mfma_f32_16x16x32_bf16(a0h, bl[ni], acc[mi0][ni], 0, 0, 0);
                acc[mi0 + 1][ni] = __builtin_amdgcn_mfma_f32_16x16x32_bf16(a1h, bh[ni], acc[mi0 + 1][ni], 0, 0, 0);
                acc[mi0 + 1][ni] = __builtin_amdgcn_mfma_f32_16x16x32_bf16(a1l, bh[ni], acc[mi0 + 1][ni], 0, 0, 0);
                acc[mi0 + 1][ni] = __builtin_amdgcn_mfma_f32_16x16x32_bf16(a1h, bl[ni], acc[mi0 + 1][ni], 0, 0, 0);
            }
            __builtin_amdgcn_s_setprio(0);
            __builtin_amdgcn_s_barrier();
        }
    }

    // ---- epilogue: C/D layout col=lane&15, row=(lane>>4)*4+reg ----
    const int orow = m0 + wr * 128 + (lane >> 4) * 4;
    const int ocol = n0 + wcn * 64 + fr;
    #pragma unroll
    for (int mi = 0; mi < 8; ++mi)
        #pragma unroll
        for (int ni = 0; ni < 4; ++ni)
            #pragma unroll
            for (int rr = 0; rr < 4; ++rr) {
                float v = acc[mi][ni][rr];
                if (SIG) v = 1.f / (1.f + expf(-v));
                Y[(size_t)(orow + mi * 16 + rr) * C_ + ocol + ni * 16] = v;
            }
}

// ---------------- WKV chunked scan, pass 1: per-chunk local end state ----
__global__ __launch_bounds__(256) void wkv_scan1(const float* __restrict__ k,
                                                 const float* __restrict__ time_decay,
                                                 float* __restrict__ chend) {
    const int c0 = (blockIdx.x * 256 + threadIdx.x) * 2;
    const int j = blockIdx.y;
    const int b = blockIdx.z;
    const float2 td = *(const float2*)&time_decay[c0];
    const float d0 = 1.f / (1.f + expf(-td.x));
    const float d1 = 1.f / (1.f + expf(-td.y));
    size_t base = ((size_t)b * T_ + (size_t)j * CHL) * C_ + c0;
    float s0 = 0.f, s1 = 0.f;
    #pragma unroll 8
    for (int t = 0; t < CHL; ++t) {
        const float2 kt = *(const float2*)&k[base];
        s0 = s0 * d0 + kt.x;
        s1 = s1 * d1 + kt.y;
        base += C_;
    }
    *(float2*)&chend[((size_t)b * NCH + j) * C_ + c0] = make_float2(s0, s1);
}

// ---------------- WKV chunked scan, pass 2: carry-in + rescan + fuse -----
__global__ __launch_bounds__(256) void wkv_scan2(const float* __restrict__ k,
                                                 const float* __restrict__ v,
                                                 const float* __restrict__ r,
                                                 const float* __restrict__ time_decay,
                                                 const float* __restrict__ time_first,
                                                 const float* __restrict__ chend,
                                                 unsigned short* __restrict__ yhi,
                                                 unsigned short* __restrict__ ylo) {
    const int c0 = (blockIdx.x * 256 + threadIdx.x) * 2;
    const int j = blockIdx.y;
    const int b = blockIdx.z;
    const float2 td = *(const float2*)&time_decay[c0];
    const float2 tf = *(const float2*)&time_first[c0];
    const float d0 = 1.f / (1.f + expf(-td.x));
    const float d1 = 1.f / (1.f + expf(-td.y));
    const float f0 = expf(tf.x);
    const float f1 = expf(tf.y);

    float dL0 = d0, dL1 = d1;           // d^CHL, CHL=64 -> 6 squarings
    #pragma unroll
    for (int i = 0; i < 6; ++i) { dL0 *= dL0; dL1 *= dL1; }

    float s0 = 0.f, s1 = 0.f;
    for (int i = 0; i < j; ++i) {
        const float2 e = *(const float2*)&chend[((size_t)b * NCH + i) * C_ + c0];
        s0 = s0 * dL0 + e.x;
        s1 = s1 * dL1 + e.y;
    }

    size_t base = ((size_t)b * T_ + (size_t)j * CHL) * C_ + c0;
    #pragma unroll 4
    for (int t = 0; t < CHL; ++t) {
        const float2 kt = *(const float2*)&k[base];
        const float2 vt = *(const float2*)&v[base];
        const float2 rt = *(const float2*)&r[base];
        s0 = s0 * d0 + kt.x;
        s1 = s1 * d1 + kt.y;
        const float y0 = rt.x * ((s0 * f0 + kt.x) * vt.x);
        const float y1 = rt.y * ((s1 * f1 + kt.y) * vt.y);
        unsigned short h0, l0, h1, l1;
        split_bf16(y0, h0, l0);
        split_bf16(y1, h1, l1);
        ushort2 ph; ph.x = h0; ph.y = h1;
        ushort2 pl; pl.x = l0; pl.y = l1;
        *(ushort2*)&yhi[base] = ph;
        *(ushort2*)&ylo[base] = pl;
        base += C_;
    }
}

// ---------------- launch ----------------
extern "C" void kernel_launch(void* const* d_in, const int* in_sizes, int n_in,
                              void* d_out, int out_size, void* d_ws, size_t ws_size,
                              hipStream_t stream) {
    const float* x          = (const float*)d_in[0];
    const float* ln_w       = (const float*)d_in[1];
    const float* ln_b       = (const float*)d_in[2];
    const float* mix_k      = (const float*)d_in[3];
    const float* mix_v      = (const float*)d_in[4];
    const float* mix_r      = (const float*)d_in[5];
    const float* time_decay = (const float*)d_in[6];
    const float* time_first = (const float*)d_in[7];
    const float* Wk         = (const float*)d_in[8];
    const float* Wv         = (const float*)d_in[9];
    const float* Wr         = (const float*)d_in[10];
    const float* Wo         = (const float*)d_in[11];
    float* out = (float*)d_out;

    // ws (211.8 MB): xt/vb 64MB | A planes hi+lo 67MB | kb 64MB | W planes 16.8MB
    const size_t planeElems = (size_t)M_ * C_;
    float* xt = (float*)d_ws;                                   // later reused as vb
    unsigned short* aphi = (unsigned short*)(xt + planeElems);
    unsigned short* aplo = aphi + planeElems;
    float* kb = (float*)(aplo + planeElems);
    unsigned short* whi = (unsigned short*)(kb + planeElems);
    unsigned short* wlo = whi + (size_t)C_ * C_;
    float* vb = xt;            // alias: xt dead after last mixsplit
    float* rb = out;           // r lives in d_out until consumed by WKV
    // chend (1MB) aliases the W-plane region: dead between v-GEMM and Wo wconv
    float* chend = (float*)whi;

    const int msBlocks = (int)(planeElems / 4) / 256;   // 16384
    const int wcBlocks = (C_ * C_ / 4) / 256;           // 4096
    const dim3 wkvGrid(C_ / 512, NCH, B_);

    // 1. LayerNorm
    ln_kernel<<<M_, 256, 0, stream>>>(x, ln_w, ln_b, xt);

    // 2. r projection first (output -> d_out)
    mixsplit_kernel<<<msBlocks, 256, 0, stream>>>(xt, mix_r, aphi, aplo);
    wconv_kernel<<<wcBlocks, 256, 0, stream>>>(Wr, whi, wlo);
    gemm_mfma<true><<<256, 512, 0, stream>>>(aphi, aplo, whi, wlo, rb);

    // 3. k projection
    mixsplit_kernel<<<msBlocks, 256, 0, stream>>>(xt, mix_k, aphi, aplo);
    wconv_kernel<<<wcBlocks, 256, 0, stream>>>(Wk, whi, wlo);
    gemm_mfma<false><<<256, 512, 0, stream>>>(aphi, aplo, whi, wlo, kb);

    // 4. v projection (last reader of xt; output overwrites xt region)
    mixsplit_kernel<<<msBlocks, 256, 0, stream>>>(xt, mix_v, aphi, aplo);
    wconv_kernel<<<wcBlocks, 256, 0, stream>>>(Wv, whi, wlo);
    gemm_mfma<false><<<256, 512, 0, stream>>>(aphi, aplo, whi, wlo, vb);

    // 5. WKV chunked scan -> split planes (A-plane region free; chend in W region)
    wkv_scan1<<<wkvGrid, 256, 0, stream>>>(kb, time_decay, chend);
    wkv_scan2<<<wkvGrid, 256, 0, stream>>>(kb, vb, rb, time_decay, time_first, chend,
                                           aphi, aplo);

    // 6. output projection (wconv overwrites chend only after scan2 done)
    wconv_kernel<<<wcBlocks, 256, 0, stream>>>(Wo, whi, wlo);
    gemm_mfma<false><<<256, 512, 0, stream>>>(aphi, aplo, whi, wlo, out);
}